// Round 1
// baseline (169.677 us; speedup 1.0000x reference)
//
#include <hip/hip_runtime.h>

#define N_PTS 1000000
#define KC 64
#define DD 8
#define NPAIR 36          // D*(D+1)/2
#define COEF_STRIDE 48    // 36 quad + 8 linear + 1 const + 3 pad (192 B, b128-aligned)

#if __has_builtin(__builtin_amdgcn_exp2f)
#define EXP2F(x) __builtin_amdgcn_exp2f(x)
#else
#define EXP2F(x) exp2f(x)
#endif
#if __has_builtin(__builtin_amdgcn_logf)
#define LOG2F_FAST(x) __builtin_amdgcn_logf(x)
#else
#define LOG2F_FAST(x) log2f(x)
#endif

// ---------------------------------------------------------------------------
// Prep: one thread per component. Build cov, Cholesky, inverse, det, fold
// softmax(prior), norm const and the -0.5*log2(e) scaling into a flat
// coefficient table coefs[K][48]:
//   arg2(n,k) = sum_{i<=j} W[t]*x_i*x_j + sum_i V[i]*x_i + C
//   prior_k * prob_k = exp2(arg2)
// ---------------------------------------------------------------------------
__global__ __launch_bounds__(64) void gmm_prep(
    const float* __restrict__ prior_logits,
    const float* __restrict__ mus,
    const float* __restrict__ cov_raw,
    float* __restrict__ coefs,
    double* __restrict__ acc)
{
    const int k = threadIdx.x;
    if (k == 0) *acc = 0.0;   // zero the global accumulator (ws is poisoned)
    if (k >= KC) return;

    const float* raw = cov_raw + k * DD * DD;
    float A[DD][DD];
    for (int i = 0; i < DD; ++i)
        for (int j = 0; j < DD; ++j)
            A[i][j] = (i == j) ? expf(raw[i * DD + i])
                               : tanhf(0.5f * (raw[i * DD + j] + raw[j * DD + i]));

    // Cholesky A = L L^T (A is SPD per problem statement)
    float L[DD][DD];
    for (int i = 0; i < DD; ++i)
        for (int j = 0; j < DD; ++j) L[i][j] = 0.f;
    for (int j = 0; j < DD; ++j) {
        float s = A[j][j];
        for (int t = 0; t < j; ++t) s -= L[j][t] * L[j][t];
        float ljj = sqrtf(s);
        L[j][j] = ljj;
        for (int i = j + 1; i < DD; ++i) {
            float v = A[i][j];
            for (int t = 0; t < j; ++t) v -= L[i][t] * L[j][t];
            L[i][j] = v / ljj;
        }
    }
    float logdet = 0.f;
    for (int j = 0; j < DD; ++j) logdet += 2.f * logf(L[j][j]);

    // Sinv = A^{-1} column by column via forward/back substitution
    float Sinv[DD][DD];
    for (int c = 0; c < DD; ++c) {
        float y[DD], z[DD];
        for (int i = 0; i < DD; ++i) {
            float v = (i == c) ? 1.f : 0.f;
            for (int t = 0; t < i; ++t) v -= L[i][t] * y[t];
            y[i] = v / L[i][i];
        }
        for (int i = DD - 1; i >= 0; --i) {
            float v = y[i];
            for (int t = i + 1; t < DD; ++t) v -= L[t][i] * z[t];
            z[i] = v / L[i][i];
        }
        for (int i = 0; i < DD; ++i) Sinv[i][c] = z[i];
    }

    const float* mu = mus + k * DD;
    float smu[DD];
    float cc = 0.f;
    for (int i = 0; i < DD; ++i) {
        float v = 0.f;
        for (int j = 0; j < DD; ++j) v += Sinv[i][j] * mu[j];
        smu[i] = v;
        cc += mu[i] * v;
    }

    // softmax(prior_logits)[k], computed redundantly per thread (K=64, cheap)
    float m = prior_logits[0];
    for (int j = 1; j < KC; ++j) m = fmaxf(m, prior_logits[j]);
    float se = 0.f;
    for (int j = 0; j < KC; ++j) se += expf(prior_logits[j] - m);
    float lprior = prior_logits[k] - m - logf(se);

    const float LOG2E = 1.44269504088896340736f;
    const float LN2PI = 1.83787706640934548356f;  // log(2*pi)
    const float s2 = -0.5f * LOG2E;

    float* w = coefs + k * COEF_STRIDE;
    int t = 0;
    for (int i = 0; i < DD; ++i)
        for (int j = i; j < DD; ++j)
            w[t++] = s2 * Sinv[i][j] * ((i == j) ? 1.f : 2.f);
    for (int i = 0; i < DD; ++i) w[NPAIR + i] = LOG2E * smu[i];
    // C = log2(prior*norm) - 0.5*log2e*(mu^T Sinv mu)
    w[44] = LOG2E * (lprior - 4.f * LN2PI) + s2 * (logdet + cc);
    w[45] = 0.f; w[46] = 0.f; w[47] = 0.f;
}

// ---------------------------------------------------------------------------
// Main: one thread per point. 36 products once, then per k: 44 FMA + exp2.
// Coefficients are block-uniform -> scalar (s_load) path, SGPR operands.
// ---------------------------------------------------------------------------
__global__ __launch_bounds__(256) void gmm_main(
    const float* __restrict__ X,
    const float* __restrict__ coefs,
    double* __restrict__ acc)
{
    const int idx = blockIdx.x * 256 + threadIdx.x;
    double ll = 0.0;
    if (idx < N_PTS) {
        const float4* xp = (const float4*)(X + (size_t)idx * DD);
        float4 va = xp[0], vb = xp[1];
        float x[DD] = {va.x, va.y, va.z, va.w, vb.x, vb.y, vb.z, vb.w};
        float p[NPAIR];
        {
            int t = 0;
            #pragma unroll
            for (int i = 0; i < DD; ++i)
                #pragma unroll
                for (int j = i; j < DD; ++j)
                    p[t++] = x[i] * x[j];
        }
        float ssum = 0.f;
        #pragma unroll 4
        for (int k = 0; k < KC; ++k) {
            const float* w = coefs + k * COEF_STRIDE;
            float a0 = w[44];
            float a1 = 0.f;
            #pragma unroll
            for (int t = 0; t < NPAIR; t += 2) {
                a0 = fmaf(w[t],     p[t],     a0);
                a1 = fmaf(w[t + 1], p[t + 1], a1);
            }
            #pragma unroll
            for (int i = 0; i < DD; i += 2) {
                a0 = fmaf(w[NPAIR + i],     x[i],     a0);
                a1 = fmaf(w[NPAIR + i + 1], x[i + 1], a1);
            }
            ssum += EXP2F(a0 + a1);
        }
        ll = (double)(LOG2F_FAST(ssum) * 0.69314718055994530942f);
    }

    // wave(64) shuffle reduce in double
    #pragma unroll
    for (int off = 32; off > 0; off >>= 1)
        ll += __shfl_down(ll, off, 64);

    __shared__ double wsum[4];
    const int lane = threadIdx.x & 63;
    const int wid  = threadIdx.x >> 6;
    if (lane == 0) wsum[wid] = ll;
    __syncthreads();
    if (threadIdx.x == 0) {
        double t = wsum[0] + wsum[1] + wsum[2] + wsum[3];
        atomicAdd(acc, t);
    }
}

__global__ void gmm_finish(const double* __restrict__ acc, float* __restrict__ out)
{
    out[0] = (float)(*acc);
}

extern "C" void kernel_launch(void* const* d_in, const int* in_sizes, int n_in,
                              void* d_out, int out_size, void* d_ws, size_t ws_size,
                              hipStream_t stream)
{
    const float* X      = (const float*)d_in[0];
    const float* prior  = (const float*)d_in[1];
    const float* mus    = (const float*)d_in[2];
    const float* covraw = (const float*)d_in[3];
    float* out = (float*)d_out;

    double* acc  = (double*)d_ws;
    float* coefs = (float*)((char*)d_ws + 256);

    gmm_prep<<<1, 64, 0, stream>>>(prior, mus, covraw, coefs, acc);
    const int nb = (N_PTS + 255) / 256;
    gmm_main<<<nb, 256, 0, stream>>>(X, coefs, acc);
    gmm_finish<<<1, 1, 0, stream>>>(acc, out);
}

// Round 5
// 147.183 us; speedup vs baseline: 1.1528x; 1.1528x over previous
//
#include <hip/hip_runtime.h>

#define N_PTS 1000000
#define KC 64
#define DD 8
#define NPAIR 36          // D*(D+1)/2
#define COEF_STRIDE 48    // 36 quad + 8 linear + 1 const + 3 pad (192 B)
#define BLK 256
#define PT_PER_TH 2
#define PTS_PER_BLK (BLK * PT_PER_TH)
#define NB ((N_PTS + PTS_PER_BLK - 1) / PTS_PER_BLK)

#if __has_builtin(__builtin_amdgcn_exp2f)
#define EXP2F(x) __builtin_amdgcn_exp2f(x)
#else
#define EXP2F(x) exp2f(x)
#endif
#if __has_builtin(__builtin_amdgcn_logf)
#define LOG2F_FAST(x) __builtin_amdgcn_logf(x)
#else
#define LOG2F_FAST(x) log2f(x)
#endif
#if __has_builtin(__builtin_amdgcn_rcpf)
#define RCPF(x) __builtin_amdgcn_rcpf(x)
#else
#define RCPF(x) (1.0f / (x))
#endif
#if __has_builtin(__builtin_amdgcn_sqrtf)
#define SQRTF(x) __builtin_amdgcn_sqrtf(x)
#else
#define SQRTF(x) sqrtf(x)
#endif

#define LOG2E 1.44269504088896340736f
#define LN2F  0.69314718055994530942f
#define LN2PI 1.83787706640934548356f

__device__ __forceinline__ float fast_tanh(float x) {
    float cl = fminf(fmaxf(x, -15.f), 15.f);
    float e = EXP2F(cl * (2.f * LOG2E));      // e^(2x)
    return (e - 1.f) * RCPF(e + 1.f);
}

// ---------------------------------------------------------------------------
// Prep: one thread per component (1 wave). Fast HW transcendentals only.
// Builds coefs[K][48]: arg2(n,k) = sum_{i<=j} W[t] x_i x_j + sum_i V[i] x_i + C
// so that prior_k * prob_k = exp2(arg2). Also zeroes acc + completion counter.
// ---------------------------------------------------------------------------
__global__ __launch_bounds__(64) void gmm_prep(
    const float* __restrict__ prior_logits,
    const float* __restrict__ mus,
    const float* __restrict__ cov_raw,
    float* __restrict__ coefs,
    double* __restrict__ acc,
    int* __restrict__ counter)
{
    const int k = threadIdx.x;
    if (k == 0) { *acc = 0.0; *counter = 0; }

    const float* raw = cov_raw + k * DD * DD;
    float A[DD][DD];
    #pragma unroll
    for (int i = 0; i < DD; ++i)
        #pragma unroll
        for (int j = 0; j < DD; ++j)
            A[i][j] = (i == j) ? EXP2F(raw[i * DD + i] * LOG2E)
                               : fast_tanh(0.5f * (raw[i * DD + j] + raw[j * DD + i]));

    // Cholesky A = L L^T
    float L[DD][DD], Dinv[DD];
    float ld2 = 0.f;  // log2(det)
    #pragma unroll
    for (int j = 0; j < DD; ++j) {
        float s = A[j][j];
        for (int t = 0; t < j; ++t) s -= L[j][t] * L[j][t];
        float ljj = SQRTF(s);
        L[j][j] = ljj;
        float rinv = RCPF(ljj);
        Dinv[j] = rinv;
        ld2 += 2.f * LOG2F_FAST(ljj);
        for (int i = j + 1; i < DD; ++i) {
            float v = A[i][j];
            for (int t = 0; t < j; ++t) v -= L[i][t] * L[j][t];
            L[i][j] = v * rinv;
        }
    }

    // Sinv = A^{-1} column by column
    float Sinv[DD][DD];
    for (int c = 0; c < DD; ++c) {
        float y[DD], z[DD];
        for (int i = 0; i < DD; ++i) {
            float v = (i == c) ? 1.f : 0.f;
            for (int t = 0; t < i; ++t) v -= L[i][t] * y[t];
            y[i] = v * Dinv[i];
        }
        for (int i = DD - 1; i >= 0; --i) {
            float v = y[i];
            for (int t = i + 1; t < DD; ++t) v -= L[t][i] * z[t];
            z[i] = v * Dinv[i];
        }
        for (int i = 0; i < DD; ++i) Sinv[i][c] = z[i];
    }

    const float* mu = mus + k * DD;
    float smu[DD];
    float cc = 0.f;
    #pragma unroll
    for (int i = 0; i < DD; ++i) {
        float v = 0.f;
        #pragma unroll
        for (int j = 0; j < DD; ++j) v += Sinv[i][j] * mu[j];
        smu[i] = v;
        cc += mu[i] * v;
    }

    // wave-parallel softmax(prior_logits)[k]
    float lg = prior_logits[k];
    float m = lg;
    #pragma unroll
    for (int off = 32; off > 0; off >>= 1)
        m = fmaxf(m, __shfl_xor(m, off, 64));
    float e = EXP2F((lg - m) * LOG2E);
    float se = e;
    #pragma unroll
    for (int off = 32; off > 0; off >>= 1)
        se += __shfl_xor(se, off, 64);
    float lprior = lg - m - LOG2F_FAST(se) * LN2F;

    const float s2 = -0.5f * LOG2E;
    float* w = coefs + k * COEF_STRIDE;
    int t = 0;
    #pragma unroll
    for (int i = 0; i < DD; ++i)
        #pragma unroll
        for (int j = i; j < DD; ++j)
            w[t++] = s2 * Sinv[i][j] * ((i == j) ? 1.f : 2.f);
    #pragma unroll
    for (int i = 0; i < DD; ++i) w[NPAIR + i] = LOG2E * smu[i];
    w[44] = LOG2E * (lprior - 4.f * LN2PI) + s2 * (ld2 * LN2F + cc);
    w[45] = 0.f; w[46] = 0.f; w[47] = 0.f;
}

// ---------------------------------------------------------------------------
// Main: 2 points/thread, coef table staged in LDS (12 KB), nested Horner
// evaluation (44 FMA per (pt,k)), exp2 accumulate; completion-counter block
// does the final global write (no separate finish kernel).
// ---------------------------------------------------------------------------
__global__ __launch_bounds__(BLK) void gmm_main(
    const float* __restrict__ X,
    const float* __restrict__ coefs,
    double* __restrict__ acc,
    int* __restrict__ counter,
    float* __restrict__ out)
{
    __shared__ float4 lcoef[KC * 12];   // 12288 B
    {
        const float4* g = (const float4*)coefs;
        #pragma unroll
        for (int r = 0; r < 3; ++r)
            lcoef[threadIdx.x + r * BLK] = g[threadIdx.x + r * BLK];
    }
    __syncthreads();

    const int p0 = blockIdx.x * PTS_PER_BLK + threadIdx.x;
    const int p1 = p0 + BLK;

    float x0[DD], x1[DD];
    if (p0 < N_PTS) {
        const float4* xp = (const float4*)(X + (size_t)p0 * DD);
        float4 a = xp[0], b = xp[1];
        x0[0]=a.x; x0[1]=a.y; x0[2]=a.z; x0[3]=a.w;
        x0[4]=b.x; x0[5]=b.y; x0[6]=b.z; x0[7]=b.w;
    } else {
        #pragma unroll
        for (int i = 0; i < DD; ++i) x0[i] = 0.f;
    }
    if (p1 < N_PTS) {
        const float4* xp = (const float4*)(X + (size_t)p1 * DD);
        float4 a = xp[0], b = xp[1];
        x1[0]=a.x; x1[1]=a.y; x1[2]=a.z; x1[3]=a.w;
        x1[4]=b.x; x1[5]=b.y; x1[6]=b.z; x1[7]=b.w;
    } else {
        #pragma unroll
        for (int i = 0; i < DD; ++i) x1[i] = 0.f;
    }

    float ss0 = 0.f, ss1 = 0.f;
    #pragma unroll 2
    for (int k = 0; k < KC; ++k) {
        float cw[COEF_STRIDE];
        {
            const float4* cp = &lcoef[k * 12];
            #pragma unroll
            for (int r = 0; r < 12; ++r) {
                float4 c = cp[r];
                cw[4*r+0] = c.x; cw[4*r+1] = c.y; cw[4*r+2] = c.z; cw[4*r+3] = c.w;
            }
        }
        float a0 = cw[44], a1 = cw[44];
        int t = 0;
        #pragma unroll
        for (int i = 0; i < DD; ++i) {
            float t0 = cw[NPAIR + i];
            float t1 = cw[NPAIR + i];
            #pragma unroll
            for (int j = i; j < DD; ++j, ++t) {
                t0 = fmaf(cw[t], x0[j], t0);
                t1 = fmaf(cw[t], x1[j], t1);
            }
            a0 = fmaf(x0[i], t0, a0);
            a1 = fmaf(x1[i], t1, a1);
        }
        ss0 += EXP2F(a0);
        ss1 += EXP2F(a1);
    }

    double ll = 0.0;
    if (p0 < N_PTS) ll += (double)(LOG2F_FAST(ss0) * LN2F);
    if (p1 < N_PTS) ll += (double)(LOG2F_FAST(ss1) * LN2F);

    // wave(64) shuffle reduce in double
    #pragma unroll
    for (int off = 32; off > 0; off >>= 1)
        ll += __shfl_down(ll, off, 64);

    __shared__ double wsum[BLK / 64];
    const int lane = threadIdx.x & 63;
    const int wid  = threadIdx.x >> 6;
    if (lane == 0) wsum[wid] = ll;
    __syncthreads();
    if (threadIdx.x == 0) {
        double t = 0.0;
        #pragma unroll
        for (int wgi = 0; wgi < BLK / 64; ++wgi) t += wsum[wgi];
        atomicAdd(acc, t);
        __threadfence();
        int old = atomicAdd(counter, 1);
        if (old == NB - 1) {
            __threadfence();
            double v = atomicAdd(acc, 0.0);   // coherent read of the full sum
            out[0] = (float)v;
        }
    }
}

extern "C" void kernel_launch(void* const* d_in, const int* in_sizes, int n_in,
                              void* d_out, int out_size, void* d_ws, size_t ws_size,
                              hipStream_t stream)
{
    const float* X      = (const float*)d_in[0];
    const float* prior  = (const float*)d_in[1];
    const float* mus    = (const float*)d_in[2];
    const float* covraw = (const float*)d_in[3];
    float* out = (float*)d_out;

    double* acc  = (double*)d_ws;
    int* counter = (int*)((char*)d_ws + 128);
    float* coefs = (float*)((char*)d_ws + 256);

    gmm_prep<<<1, 64, 0, stream>>>(prior, mus, covraw, coefs, acc, counter);
    gmm_main<<<NB, BLK, 0, stream>>>(X, coefs, acc, counter, out);
}

// Round 7
// 119.141 us; speedup vs baseline: 1.4242x; 1.2354x over previous
//
#include <hip/hip_runtime.h>

#define N_PTS 1000000
#define KC 64
#define DD 8
#define NPAIR 36          // D*(D+1)/2
#define COEF_STRIDE 48    // 36 quad + 8 linear + 1 const + 3 pad (192 B)
#define BLK 256
#define PT_PER_TH 2
#define PTS_PER_BLK (BLK * PT_PER_TH)
#define NB ((N_PTS + PTS_PER_BLK - 1) / PTS_PER_BLK)

#if __has_builtin(__builtin_amdgcn_exp2f)
#define EXP2F(x) __builtin_amdgcn_exp2f(x)
#else
#define EXP2F(x) exp2f(x)
#endif
#if __has_builtin(__builtin_amdgcn_logf)
#define LOG2F_FAST(x) __builtin_amdgcn_logf(x)
#else
#define LOG2F_FAST(x) log2f(x)
#endif
#if __has_builtin(__builtin_amdgcn_rcpf)
#define RCPF(x) __builtin_amdgcn_rcpf(x)
#else
#define RCPF(x) (1.0f / (x))
#endif
#if __has_builtin(__builtin_amdgcn_sqrtf)
#define SQRTF(x) __builtin_amdgcn_sqrtf(x)
#else
#define SQRTF(x) sqrtf(x)
#endif

#define LOG2E 1.44269504088896340736f
#define LN2F  0.69314718055994530942f
#define LN2PI 1.83787706640934548356f

__device__ __forceinline__ float fast_tanh(float x) {
    float cl = fminf(fmaxf(x, -15.f), 15.f);
    float e = EXP2F(cl * (2.f * LOG2E));      // e^(2x)
    return (e - 1.f) * RCPF(e + 1.f);
}

// ---------------------------------------------------------------------------
// Prep: one thread per component (1 wave). EVERY loop fully unrolled so all
// array indices are compile-time constants -> arrays live in VGPRs, not
// scratch (rule #20: runtime-indexed arrays go to local memory; that was the
// ~60 us cost of the previous prep). Also detects whether the quadratic
// coefficient block is identical across all K components (it is when
// cov_raw is constant across k) and publishes a flag for the fast path.
// ---------------------------------------------------------------------------
__global__ __launch_bounds__(64, 1) void gmm_prep(
    const float* __restrict__ prior_logits,
    const float* __restrict__ mus,
    const float* __restrict__ cov_raw,
    float* __restrict__ coefs,
    double* __restrict__ acc,
    int* __restrict__ counter,
    int* __restrict__ flag)
{
    const int k = threadIdx.x;
    if (k == 0) { *acc = 0.0; *counter = 0; }

    const float* raw = cov_raw + k * DD * DD;
    float A[DD][DD];
    #pragma unroll
    for (int i = 0; i < DD; ++i)
        #pragma unroll
        for (int j = 0; j < DD; ++j)
            A[i][j] = (i == j) ? EXP2F(raw[i * DD + i] * LOG2E)
                               : fast_tanh(0.5f * (raw[i * DD + j] + raw[j * DD + i]));

    // Cholesky A = L L^T
    float L[DD][DD], Dinv[DD];
    float ld2 = 0.f;  // log2(det)
    #pragma unroll
    for (int j = 0; j < DD; ++j) {
        float s = A[j][j];
        #pragma unroll
        for (int t = 0; t < j; ++t) s -= L[j][t] * L[j][t];
        float ljj = SQRTF(s);
        L[j][j] = ljj;
        float rinv = RCPF(ljj);
        Dinv[j] = rinv;
        ld2 += 2.f * LOG2F_FAST(ljj);
        #pragma unroll
        for (int i = j + 1; i < DD; ++i) {
            float v = A[i][j];
            #pragma unroll
            for (int t = 0; t < j; ++t) v -= L[i][t] * L[j][t];
            L[i][j] = v * rinv;
        }
    }

    // Sinv = A^{-1} column by column (all unrolled -> registers)
    float Sinv[DD][DD];
    #pragma unroll
    for (int c = 0; c < DD; ++c) {
        float y[DD], z[DD];
        #pragma unroll
        for (int i = 0; i < DD; ++i) {
            float v = (i == c) ? 1.f : 0.f;
            #pragma unroll
            for (int t = 0; t < i; ++t) v -= L[i][t] * y[t];
            y[i] = v * Dinv[i];
        }
        #pragma unroll
        for (int i = DD - 1; i >= 0; --i) {
            float v = y[i];
            #pragma unroll
            for (int t = i + 1; t < DD; ++t) v -= L[t][i] * z[t];
            z[i] = v * Dinv[i];
        }
        #pragma unroll
        for (int i = 0; i < DD; ++i) Sinv[i][c] = z[i];
    }

    const float* mu = mus + k * DD;
    float smu[DD];
    float cc = 0.f;
    #pragma unroll
    for (int i = 0; i < DD; ++i) {
        float v = 0.f;
        #pragma unroll
        for (int j = 0; j < DD; ++j) v += Sinv[i][j] * mu[j];
        smu[i] = v;
        cc += mu[i] * v;
    }

    // wave-parallel softmax(prior_logits)[k]
    float lg = prior_logits[k];
    float m = lg;
    #pragma unroll
    for (int off = 32; off > 0; off >>= 1)
        m = fmaxf(m, __shfl_xor(m, off, 64));
    float e = EXP2F((lg - m) * LOG2E);
    float se = e;
    #pragma unroll
    for (int off = 32; off > 0; off >>= 1)
        se += __shfl_xor(se, off, 64);
    float lprior = lg - m - LOG2F_FAST(se) * LN2F;

    const float s2 = -0.5f * LOG2E;
    float qw[NPAIR];
    {
        int t = 0;
        #pragma unroll
        for (int i = 0; i < DD; ++i)
            #pragma unroll
            for (int j = i; j < DD; ++j) {
                qw[t] = s2 * Sinv[i][j] * ((i == j) ? 1.f : 2.f);
                ++t;
            }
    }

    float* w = coefs + k * COEF_STRIDE;
    #pragma unroll
    for (int t = 0; t < NPAIR; ++t) w[t] = qw[t];
    #pragma unroll
    for (int i = 0; i < DD; ++i) w[NPAIR + i] = LOG2E * smu[i];
    w[44] = LOG2E * (lprior - 4.f * LN2PI) + s2 * (ld2 * LN2F + cc);
    w[45] = 0.f; w[46] = 0.f; w[47] = 0.f;

    // all-k quad-block equality check (bitwise; NaN -> flag 0 -> general path)
    int eq = 1;
    #pragma unroll
    for (int t = 0; t < NPAIR; ++t) {
        float l0v = __shfl(qw[t], 0, 64);
        eq &= (qw[t] == l0v) ? 1 : 0;
    }
    unsigned long long b = __ballot(eq != 0);
    if (k == 0) *flag = (b == 0xFFFFFFFFFFFFFFFFULL) ? 1 : 0;
}

// ---------------------------------------------------------------------------
// Main: 2 points/thread, coef table in LDS.
//  fast path (shared quadratic form across k): xSx once per point (44 FMA),
//    then per k: 1 add + 8 FMA + exp2 + acc  (~11 VALU slots vs 46).
//  general path: round-5 nested-Horner loop (44 FMA per (pt,k)).
// Completion-counter block writes the final scalar (no 3rd kernel).
// ---------------------------------------------------------------------------
__global__ __launch_bounds__(BLK) void gmm_main(
    const float* __restrict__ X,
    const float* __restrict__ coefs,
    const int* __restrict__ flag,
    double* __restrict__ acc,
    int* __restrict__ counter,
    float* __restrict__ out)
{
    __shared__ float4 lcoef[KC * 12];   // 12288 B
    {
        const float4* g = (const float4*)coefs;
        #pragma unroll
        for (int r = 0; r < 3; ++r)
            lcoef[threadIdx.x + r * BLK] = g[threadIdx.x + r * BLK];
    }
    __syncthreads();

    const int p0 = blockIdx.x * PTS_PER_BLK + threadIdx.x;
    const int p1 = p0 + BLK;

    float x0[DD], x1[DD];
    if (p0 < N_PTS) {
        const float4* xp = (const float4*)(X + (size_t)p0 * DD);
        float4 a = xp[0], b = xp[1];
        x0[0]=a.x; x0[1]=a.y; x0[2]=a.z; x0[3]=a.w;
        x0[4]=b.x; x0[5]=b.y; x0[6]=b.z; x0[7]=b.w;
    } else {
        #pragma unroll
        for (int i = 0; i < DD; ++i) x0[i] = 0.f;
    }
    if (p1 < N_PTS) {
        const float4* xp = (const float4*)(X + (size_t)p1 * DD);
        float4 a = xp[0], b = xp[1];
        x1[0]=a.x; x1[1]=a.y; x1[2]=a.z; x1[3]=a.w;
        x1[4]=b.x; x1[5]=b.y; x1[6]=b.z; x1[7]=b.w;
    } else {
        #pragma unroll
        for (int i = 0; i < DD; ++i) x1[i] = 0.f;
    }

    float ss0 = 0.f, ss1 = 0.f;

    if (*flag) {
        // ---- fast path: quadratic form shared across all k ----
        float Q[NPAIR];
        {
            #pragma unroll
            for (int r = 0; r < 9; ++r) {
                float4 c = lcoef[r];
                Q[4*r+0] = c.x; Q[4*r+1] = c.y; Q[4*r+2] = c.z; Q[4*r+3] = c.w;
            }
        }
        float q0 = 0.f, q1 = 0.f;
        {
            int t = 0;
            #pragma unroll
            for (int i = 0; i < DD; ++i) {
                float s0 = 0.f, s1 = 0.f;
                #pragma unroll
                for (int j = i; j < DD; ++j, ++t) {
                    s0 = fmaf(Q[t], x0[j], s0);
                    s1 = fmaf(Q[t], x1[j], s1);
                }
                q0 = fmaf(x0[i], s0, q0);
                q1 = fmaf(x1[i], s1, q1);
            }
        }
        #pragma unroll 4
        for (int k = 0; k < KC; ++k) {
            const float4* cp = &lcoef[k * 12 + 9];
            float4 l0 = cp[0], l1 = cp[1], c4 = cp[2];
            float a0 = c4.x + q0;
            float a1 = c4.x + q1;
            a0 = fmaf(l0.x, x0[0], a0);  a1 = fmaf(l0.x, x1[0], a1);
            a0 = fmaf(l0.y, x0[1], a0);  a1 = fmaf(l0.y, x1[1], a1);
            a0 = fmaf(l0.z, x0[2], a0);  a1 = fmaf(l0.z, x1[2], a1);
            a0 = fmaf(l0.w, x0[3], a0);  a1 = fmaf(l0.w, x1[3], a1);
            a0 = fmaf(l1.x, x0[4], a0);  a1 = fmaf(l1.x, x1[4], a1);
            a0 = fmaf(l1.y, x0[5], a0);  a1 = fmaf(l1.y, x1[5], a1);
            a0 = fmaf(l1.z, x0[6], a0);  a1 = fmaf(l1.z, x1[6], a1);
            a0 = fmaf(l1.w, x0[7], a0);  a1 = fmaf(l1.w, x1[7], a1);
            ss0 += EXP2F(a0);
            ss1 += EXP2F(a1);
        }
    } else {
        // ---- general path (round-5 loop) ----
        #pragma unroll 2
        for (int k = 0; k < KC; ++k) {
            float cw[COEF_STRIDE];
            {
                const float4* cp = &lcoef[k * 12];
                #pragma unroll
                for (int r = 0; r < 12; ++r) {
                    float4 c = cp[r];
                    cw[4*r+0] = c.x; cw[4*r+1] = c.y; cw[4*r+2] = c.z; cw[4*r+3] = c.w;
                }
            }
            float a0 = cw[44], a1 = cw[44];
            int t = 0;
            #pragma unroll
            for (int i = 0; i < DD; ++i) {
                float t0 = cw[NPAIR + i];
                float t1 = cw[NPAIR + i];
                #pragma unroll
                for (int j = i; j < DD; ++j, ++t) {
                    t0 = fmaf(cw[t], x0[j], t0);
                    t1 = fmaf(cw[t], x1[j], t1);
                }
                a0 = fmaf(x0[i], t0, a0);
                a1 = fmaf(x1[i], t1, a1);
            }
            ss0 += EXP2F(a0);
            ss1 += EXP2F(a1);
        }
    }

    double ll = 0.0;
    if (p0 < N_PTS) ll += (double)(LOG2F_FAST(ss0) * LN2F);
    if (p1 < N_PTS) ll += (double)(LOG2F_FAST(ss1) * LN2F);

    // wave(64) shuffle reduce in double
    #pragma unroll
    for (int off = 32; off > 0; off >>= 1)
        ll += __shfl_down(ll, off, 64);

    __shared__ double wsum[BLK / 64];
    const int lane = threadIdx.x & 63;
    const int wid  = threadIdx.x >> 6;
    if (lane == 0) wsum[wid] = ll;
    __syncthreads();
    if (threadIdx.x == 0) {
        double t = 0.0;
        #pragma unroll
        for (int wgi = 0; wgi < BLK / 64; ++wgi) t += wsum[wgi];
        atomicAdd(acc, t);
        __threadfence();
        int old = atomicAdd(counter, 1);
        if (old == NB - 1) {
            __threadfence();
            double v = atomicAdd(acc, 0.0);   // coherent read of the full sum
            out[0] = (float)v;
        }
    }
}

extern "C" void kernel_launch(void* const* d_in, const int* in_sizes, int n_in,
                              void* d_out, int out_size, void* d_ws, size_t ws_size,
                              hipStream_t stream)
{
    const float* X      = (const float*)d_in[0];
    const float* prior  = (const float*)d_in[1];
    const float* mus    = (const float*)d_in[2];
    const float* covraw = (const float*)d_in[3];
    float* out = (float*)d_out;

    double* acc  = (double*)d_ws;
    int* counter = (int*)((char*)d_ws + 128);
    int* flag    = (int*)((char*)d_ws + 132);
    float* coefs = (float*)((char*)d_ws + 256);

    gmm_prep<<<1, 64, 0, stream>>>(prior, mus, covraw, coefs, acc, counter, flag);
    gmm_main<<<NB, BLK, 0, stream>>>(X, coefs, flag, acc, counter, out);
}

// Round 9
// 104.035 us; speedup vs baseline: 1.6310x; 1.1452x over previous
//
#include <hip/hip_runtime.h>

#define N_PTS 1000000
#define KC 64
#define DD 8
#define NPAIR 36          // D*(D+1)/2
#define COEF_STRIDE 48    // 36 quad + 8 linear + 1 const + 3 pad (192 B)
#define BLK 256
#define PT_PER_TH 4
#define PTS_PER_BLK (BLK * PT_PER_TH)
#define NB ((N_PTS + PTS_PER_BLK - 1) / PTS_PER_BLK)

#if __has_builtin(__builtin_amdgcn_exp2f)
#define EXP2F(x) __builtin_amdgcn_exp2f(x)
#else
#define EXP2F(x) exp2f(x)
#endif
#if __has_builtin(__builtin_amdgcn_logf)
#define LOG2F_FAST(x) __builtin_amdgcn_logf(x)
#else
#define LOG2F_FAST(x) log2f(x)
#endif
#if __has_builtin(__builtin_amdgcn_rcpf)
#define RCPF(x) __builtin_amdgcn_rcpf(x)
#else
#define RCPF(x) (1.0f / (x))
#endif
#if __has_builtin(__builtin_amdgcn_sqrtf)
#define SQRTF(x) __builtin_amdgcn_sqrtf(x)
#else
#define SQRTF(x) sqrtf(x)
#endif

#define LOG2E 1.44269504088896340736f
#define LN2F  0.69314718055994530942f
#define LN2PI 1.83787706640934548356f

__device__ __forceinline__ float fast_tanh(float x) {
    float cl = fminf(fmaxf(x, -15.f), 15.f);
    float e = EXP2F(cl * (2.f * LOG2E));      // e^(2x)
    return (e - 1.f) * RCPF(e + 1.f);
}

// ---------------------------------------------------------------------------
// Prep: one thread per component (1 wave). Fully unrolled (rule #20: all
// indices compile-time -> VGPRs not scratch). Publishes coefs[K][48] with
// arg2(n,k) = sum_{i<=j} W x_i x_j + sum_i V x_i + C, prior_k*prob_k=exp2(arg2)
// plus a flag saying whether the quadratic block W is identical across all k.
// ---------------------------------------------------------------------------
__global__ __launch_bounds__(64, 1) void gmm_prep(
    const float* __restrict__ prior_logits,
    const float* __restrict__ mus,
    const float* __restrict__ cov_raw,
    float* __restrict__ coefs,
    double* __restrict__ acc,
    int* __restrict__ counter,
    int* __restrict__ flag)
{
    const int k = threadIdx.x;
    if (k == 0) { *acc = 0.0; *counter = 0; }

    const float* raw = cov_raw + k * DD * DD;
    float A[DD][DD];
    #pragma unroll
    for (int i = 0; i < DD; ++i)
        #pragma unroll
        for (int j = 0; j < DD; ++j)
            A[i][j] = (i == j) ? EXP2F(raw[i * DD + i] * LOG2E)
                               : fast_tanh(0.5f * (raw[i * DD + j] + raw[j * DD + i]));

    // Cholesky A = L L^T
    float L[DD][DD], Dinv[DD];
    float ld2 = 0.f;  // log2(det)
    #pragma unroll
    for (int j = 0; j < DD; ++j) {
        float s = A[j][j];
        #pragma unroll
        for (int t = 0; t < j; ++t) s -= L[j][t] * L[j][t];
        float ljj = SQRTF(s);
        L[j][j] = ljj;
        float rinv = RCPF(ljj);
        Dinv[j] = rinv;
        ld2 += 2.f * LOG2F_FAST(ljj);
        #pragma unroll
        for (int i = j + 1; i < DD; ++i) {
            float v = A[i][j];
            #pragma unroll
            for (int t = 0; t < j; ++t) v -= L[i][t] * L[j][t];
            L[i][j] = v * rinv;
        }
    }

    // Sinv = A^{-1} column by column (all unrolled -> registers)
    float Sinv[DD][DD];
    #pragma unroll
    for (int c = 0; c < DD; ++c) {
        float y[DD], z[DD];
        #pragma unroll
        for (int i = 0; i < DD; ++i) {
            float v = (i == c) ? 1.f : 0.f;
            #pragma unroll
            for (int t = 0; t < i; ++t) v -= L[i][t] * y[t];
            y[i] = v * Dinv[i];
        }
        #pragma unroll
        for (int i = DD - 1; i >= 0; --i) {
            float v = y[i];
            #pragma unroll
            for (int t = i + 1; t < DD; ++t) v -= L[t][i] * z[t];
            z[i] = v * Dinv[i];
        }
        #pragma unroll
        for (int i = 0; i < DD; ++i) Sinv[i][c] = z[i];
    }

    const float* mu = mus + k * DD;
    float smu[DD];
    float cc = 0.f;
    #pragma unroll
    for (int i = 0; i < DD; ++i) {
        float v = 0.f;
        #pragma unroll
        for (int j = 0; j < DD; ++j) v += Sinv[i][j] * mu[j];
        smu[i] = v;
        cc += mu[i] * v;
    }

    // wave-parallel softmax(prior_logits)[k]
    float lg = prior_logits[k];
    float m = lg;
    #pragma unroll
    for (int off = 32; off > 0; off >>= 1)
        m = fmaxf(m, __shfl_xor(m, off, 64));
    float e = EXP2F((lg - m) * LOG2E);
    float se = e;
    #pragma unroll
    for (int off = 32; off > 0; off >>= 1)
        se += __shfl_xor(se, off, 64);
    float lprior = lg - m - LOG2F_FAST(se) * LN2F;

    const float s2 = -0.5f * LOG2E;
    float qw[NPAIR];
    {
        int t = 0;
        #pragma unroll
        for (int i = 0; i < DD; ++i)
            #pragma unroll
            for (int j = i; j < DD; ++j) {
                qw[t] = s2 * Sinv[i][j] * ((i == j) ? 1.f : 2.f);
                ++t;
            }
    }

    float* w = coefs + k * COEF_STRIDE;
    #pragma unroll
    for (int t = 0; t < NPAIR; ++t) w[t] = qw[t];
    #pragma unroll
    for (int i = 0; i < DD; ++i) w[NPAIR + i] = LOG2E * smu[i];
    w[44] = LOG2E * (lprior - 4.f * LN2PI) + s2 * (ld2 * LN2F + cc);
    w[45] = 0.f; w[46] = 0.f; w[47] = 0.f;

    // all-k quad-block equality check (bitwise; NaN -> flag 0 -> general path)
    int eq = 1;
    #pragma unroll
    for (int t = 0; t < NPAIR; ++t) {
        float l0v = __shfl(qw[t], 0, 64);
        eq &= (qw[t] == l0v) ? 1 : 0;
    }
    unsigned long long b = __ballot(eq != 0);
    if (k == 0) *flag = (b == 0xFFFFFFFFFFFFFFFFULL) ? 1 : 0;
}

// ---------------------------------------------------------------------------
// Main: 4 points/thread (R7 showed 2 pt/th is LDS-throughput-bound: 3 uniform
// ds_read_b128 per k-iter ~30 LDS-cyc vs 44 VALU-cyc, LDS shared by 4 SIMDs
// -> VALUBusy 40%. 4 pt/th doubles FMAs per coef read -> VALU-bound ~75%).
// Fast path also factors exp2(q) out of the k-loop:
//   ll = ln2 * (q + log2( sum_k exp2(dot_k + c_k) ))
// saving the per-k "+q" add (10 VALU instr per pt per k).
// ---------------------------------------------------------------------------
__global__ __launch_bounds__(BLK) void gmm_main(
    const float* __restrict__ X,
    const float* __restrict__ coefs,
    const int* __restrict__ flag,
    double* __restrict__ acc,
    int* __restrict__ counter,
    float* __restrict__ out)
{
    __shared__ float4 lcoef[KC * 12];   // 12288 B
    {
        const float4* g = (const float4*)coefs;
        #pragma unroll
        for (int r = 0; r < 3; ++r)
            lcoef[threadIdx.x + r * BLK] = g[threadIdx.x + r * BLK];
    }
    __syncthreads();

    const int pbase = blockIdx.x * PTS_PER_BLK + threadIdx.x;

    float x[PT_PER_TH][DD];
    bool  valid[PT_PER_TH];
    #pragma unroll
    for (int p = 0; p < PT_PER_TH; ++p) {
        const int pi = pbase + p * BLK;
        valid[p] = (pi < N_PTS);
        if (valid[p]) {
            const float4* xp = (const float4*)(X + (size_t)pi * DD);
            float4 a = xp[0], b = xp[1];
            x[p][0]=a.x; x[p][1]=a.y; x[p][2]=a.z; x[p][3]=a.w;
            x[p][4]=b.x; x[p][5]=b.y; x[p][6]=b.z; x[p][7]=b.w;
        } else {
            #pragma unroll
            for (int i = 0; i < DD; ++i) x[p][i] = 0.f;
        }
    }

    double ll = 0.0;

    if (*flag) {
        // ---- fast path: quadratic form shared across all k ----
        float q[PT_PER_TH];
        {
            float Q[NPAIR];
            #pragma unroll
            for (int r = 0; r < 9; ++r) {
                float4 c = lcoef[r];
                Q[4*r+0] = c.x; Q[4*r+1] = c.y; Q[4*r+2] = c.z; Q[4*r+3] = c.w;
            }
            #pragma unroll
            for (int p = 0; p < PT_PER_TH; ++p) {
                float qq = 0.f;
                int t = 0;
                #pragma unroll
                for (int i = 0; i < DD; ++i) {
                    float s = 0.f;
                    #pragma unroll
                    for (int j = i; j < DD; ++j, ++t)
                        s = fmaf(Q[t], x[p][j], s);
                    qq = fmaf(x[p][i], s, qq);
                }
                q[p] = qq;
            }
        }

        float ss[PT_PER_TH];
        #pragma unroll
        for (int p = 0; p < PT_PER_TH; ++p) ss[p] = 0.f;

        #pragma unroll 4
        for (int k = 0; k < KC; ++k) {
            const float4* cp = &lcoef[k * 12 + 9];
            float4 l0 = cp[0], l1 = cp[1], c4 = cp[2];
            #pragma unroll
            for (int p = 0; p < PT_PER_TH; ++p) {
                float a = fmaf(l0.x, x[p][0], c4.x);
                a = fmaf(l0.y, x[p][1], a);
                a = fmaf(l0.z, x[p][2], a);
                a = fmaf(l0.w, x[p][3], a);
                a = fmaf(l1.x, x[p][4], a);
                a = fmaf(l1.y, x[p][5], a);
                a = fmaf(l1.z, x[p][6], a);
                a = fmaf(l1.w, x[p][7], a);
                ss[p] += EXP2F(a);
            }
        }

        #pragma unroll
        for (int p = 0; p < PT_PER_TH; ++p)
            if (valid[p])
                ll += (double)((q[p] + LOG2F_FAST(ss[p])) * LN2F);
    } else {
        // ---- general path: per-k full quadratic (correctness fallback) ----
        float ss[PT_PER_TH];
        #pragma unroll
        for (int p = 0; p < PT_PER_TH; ++p) ss[p] = 0.f;

        for (int k = 0; k < KC; ++k) {
            float cw[COEF_STRIDE];
            {
                const float4* cp = &lcoef[k * 12];
                #pragma unroll
                for (int r = 0; r < 12; ++r) {
                    float4 c = cp[r];
                    cw[4*r+0] = c.x; cw[4*r+1] = c.y; cw[4*r+2] = c.z; cw[4*r+3] = c.w;
                }
            }
            #pragma unroll
            for (int p = 0; p < PT_PER_TH; ++p) {
                float a = cw[44];
                int t = 0;
                #pragma unroll
                for (int i = 0; i < DD; ++i) {
                    float s = cw[NPAIR + i];
                    #pragma unroll
                    for (int j = i; j < DD; ++j, ++t)
                        s = fmaf(cw[t], x[p][j], s);
                    a = fmaf(x[p][i], s, a);
                }
                ss[p] += EXP2F(a);
            }
        }

        #pragma unroll
        for (int p = 0; p < PT_PER_TH; ++p)
            if (valid[p])
                ll += (double)(LOG2F_FAST(ss[p]) * LN2F);
    }

    // wave(64) shuffle reduce in double
    #pragma unroll
    for (int off = 32; off > 0; off >>= 1)
        ll += __shfl_down(ll, off, 64);

    __shared__ double wsum[BLK / 64];
    const int lane = threadIdx.x & 63;
    const int wid  = threadIdx.x >> 6;
    if (lane == 0) wsum[wid] = ll;
    __syncthreads();
    if (threadIdx.x == 0) {
        double t = 0.0;
        #pragma unroll
        for (int wgi = 0; wgi < BLK / 64; ++wgi) t += wsum[wgi];
        atomicAdd(acc, t);
        __threadfence();
        int old = atomicAdd(counter, 1);
        if (old == NB - 1) {
            __threadfence();
            double v = atomicAdd(acc, 0.0);   // coherent read of the full sum
            out[0] = (float)v;
        }
    }
}

extern "C" void kernel_launch(void* const* d_in, const int* in_sizes, int n_in,
                              void* d_out, int out_size, void* d_ws, size_t ws_size,
                              hipStream_t stream)
{
    const float* X      = (const float*)d_in[0];
    const float* prior  = (const float*)d_in[1];
    const float* mus    = (const float*)d_in[2];
    const float* covraw = (const float*)d_in[3];
    float* out = (float*)d_out;

    double* acc  = (double*)d_ws;
    int* counter = (int*)((char*)d_ws + 128);
    int* flag    = (int*)((char*)d_ws + 132);
    float* coefs = (float*)((char*)d_ws + 256);

    gmm_prep<<<1, 64, 0, stream>>>(prior, mus, covraw, coefs, acc, counter, flag);
    gmm_main<<<NB, BLK, 0, stream>>>(X, coefs, flag, acc, counter, out);
}